// Round 3
// baseline (268.474 us; speedup 1.0000x reference)
//
#include <hip/hip_runtime.h>
#include <hip/hip_bf16.h>

#define B_   16
#define CIN  256
#define CO   128
#define HW   4096

typedef __attribute__((ext_vector_type(8))) short short8;
typedef __attribute__((ext_vector_type(4))) float f32x4;
typedef __attribute__((ext_vector_type(4))) unsigned u32x4;

__device__ __forceinline__ short f32_to_bf16_rne(float f) {
    union { float f; unsigned u; } v; v.f = f;
    unsigned u = v.u;
    u += 0x7fffu + ((u >> 16) & 1u);
    return (short)(u >> 16);
}

// ---------------------------------------------------------------------------
// Weight pre-convert: wbf[0][co][ci] = bf16(theta_w), wbf[1][co][ci] = bf16(phi_w)
// ---------------------------------------------------------------------------
__global__ __launch_bounds__(256) void wconv_kernel(
    const float* __restrict__ tw, const float* __restrict__ pw,
    short* __restrict__ wbf)
{
    const int idx = blockIdx.x * 256 + threadIdx.x;     // 0 .. 2*CO*CIN-1
    const float v = (idx < CO * CIN) ? tw[idx] : pw[idx - CO * CIN];
    wbf[idx] = f32_to_bf16_rne(v);
}

// ---------------------------------------------------------------------------
// Projection v3: out_T[b][i][co] = sum_ci x[b][ci][i] * w[co][ci] + bias[co]
// grid 2048, block 256 (4 waves), XCD-swizzled by batch.
// Staging mirrors maxgemm's PROVEN pattern: bf16 LDS tile [64 i][64 ci]
// (128B rows), 16B chunks XOR-swizzled by (row&7) -> ~2-way conflicts max.
// Each thread: 16 scalar f32 loads (stride HW, 256B coalesced across wave),
// cvt+pack in regs, ONE ds_write_b128 per row-chunk. 4 K-chunks of 64,
// LDS + weight-fragment double buffered; 16 loads/thread in flight across
// each barrier. ~100 VGPR, 16 KB LDS -> 4 blocks/CU.
// ---------------------------------------------------------------------------
__global__ __launch_bounds__(256, 4) void proj_kernel(
    const float* __restrict__ xg, const float* __restrict__ xq,
    const float* __restrict__ tb, const float* __restrict__ pb,
    const short* __restrict__ wbf,
    short* __restrict__ tT, short* __restrict__ pT)
{
    const int n     = blockIdx.x;
    const int xcd   = n & 7;
    const int q     = n >> 3;            // 0..255
    const int b     = xcd + 8 * (q & 1);
    const int r2    = q >> 1;            // 0..127
    const int which = r2 & 1;
    const int itile = r2 >> 1;           // 0..63

    const float* x    = which ? xq : xg;
    const float* bias = which ? pb : tb;
    const short* wb   = wbf + which * CO * CIN;
    short*       out  = which ? pT : tT;

    const int i0   = itile * 64;
    const int tid  = threadIdx.x;
    const int lane = tid & 63;
    const int wv   = tid >> 6;          // wave 0..3 -> co range [wv*32, wv*32+32)
    const int nrow = lane & 15;
    const int quad = lane >> 4;

    const int si   = tid & 63;          // row this thread stages (distinct per wave)
    const int cig  = tid >> 6;          // ci-group 0..3

    __shared__ __align__(16) short xT[2][64][64];   // [buf][i][ci] bf16, swizzled chunks

    f32x4 acc[4][2] = {};               // 4 m-subtiles (i) x 2 n-subtiles (co)

    float bias_v[2];
    bias_v[0] = bias[wv * 32 + 0  + nrow];
    bias_v[1] = bias[wv * 32 + 16 + nrow];

    const float* xb = x + (long)b * CIN * HW + i0 + si;   // this thread's i-column

    // ---- staging: 16 scalar f32 (stride HW) per thread per chunk
    float fst[2][8];
    auto stage_load = [&](int c) {
        const float* src = xb + (long)(c * 64) * HW;
        #pragma unroll
        for (int ro = 0; ro < 2; ro++)
            #pragma unroll
            for (int r = 0; r < 8; r++)
                fst[ro][r] = src[(long)((ro * 4 + cig) * 8 + r) * HW];
    };
    auto stage_write = [&](int buf) {
        #pragma unroll
        for (int ro = 0; ro < 2; ro++) {
            u32x4 d;
            #pragma unroll
            for (int p = 0; p < 4; p++) {
                const unsigned lo = (unsigned short)f32_to_bf16_rne(fst[ro][2 * p]);
                const unsigned hi = (unsigned short)f32_to_bf16_rne(fst[ro][2 * p + 1]);
                d[p] = lo | (hi << 16);
            }
            const int ck = (ro * 4 + cig) ^ (si & 7);   // XOR-swizzled 16B chunk
            *(u32x4*)&xT[buf][si][ck * 8] = d;
        }
    };

    // ---- weight fragments: double-buffered per chunk (32 VGPR)
    short8 wf[2][2][2];                 // [buf][ks][nt]
    auto wload = [&](int c, int buf) {
        #pragma unroll
        for (int ks = 0; ks < 2; ks++)
            #pragma unroll
            for (int nt = 0; nt < 2; nt++)
                wf[buf][ks][nt] = *(const short8*)(
                    wb + (wv * 32 + nt * 16 + nrow) * CIN + c * 64 + ks * 32 + quad * 8);
    };

    auto compute = [&](int buf) {
        #pragma unroll
        for (int ks = 0; ks < 2; ks++)
            #pragma unroll
            for (int mt = 0; mt < 4; mt++) {
                const int row = mt * 16 + nrow;
                const int ck  = (ks * 4 + quad) ^ (row & 7);
                const short8 a = *(const short8*)&xT[buf][row][ck * 8];
                acc[mt][0] = __builtin_amdgcn_mfma_f32_16x16x32_bf16(a, wf[buf][ks][0], acc[mt][0], 0, 0, 0);
                acc[mt][1] = __builtin_amdgcn_mfma_f32_16x16x32_bf16(a, wf[buf][ks][1], acc[mt][1], 0, 0, 0);
            }
    };

    wload(0, 0);
    stage_load(0);
    stage_write(0);
    #pragma unroll
    for (int c = 0; c < 4; c++) {
        __syncthreads();
        if (c < 3) { stage_load(c + 1); wload(c + 1, (c + 1) & 1); }  // deep prefetch
        compute(c & 1);
        if (c < 3) stage_write((c + 1) & 1);
    }

    // ---- store: D layout col = lane&15 (co), row = quad*4 + reg (i)
    #pragma unroll
    for (int mt = 0; mt < 4; mt++)
        #pragma unroll
        for (int nt = 0; nt < 2; nt++) {
            const int co = wv * 32 + nt * 16 + nrow;
            #pragma unroll
            for (int r = 0; r < 4; r++) {
                const int il = mt * 16 + quad * 4 + r;
                out[((long)b * HW + i0 + il) * CO + co] =
                    f32_to_bf16_rne(acc[mt][nt][r] + bias_v[nt]);
            }
        }
}

// ---------------------------------------------------------------------------
// Max-GEMM v2: pmax[jh][b][i] = max_{j in half jh} sum_c tT[b][i][c]*pT[b][j][c]
// (unchanged from previous round)
// ---------------------------------------------------------------------------
__global__ __launch_bounds__(256, 1) void maxgemm_kernel(
    const short* __restrict__ tT, const short* __restrict__ pT,
    float* __restrict__ pmax)
{
    const int n     = blockIdx.x;
    const int b     = (n & 7) + 8 * ((n >> 3) & 1);
    const int mm    = n >> 4;            // 0..15
    const int itile = mm & 7;            // 0..7
    const int jhalf = mm >> 3;           // 0..1
    const int i0    = itile * 512;
    const int j0    = jhalf * 2048;
    const int tid   = threadIdx.x;
    const int lane  = tid & 63;
    const int wv    = tid >> 6;
    const int nrow  = lane & 15;
    const int quad  = lane >> 4;

    __shared__ short bT[2][64][128];     // 32 KB, unpadded, XOR-swizzled chunks

    // ---- loop-invariant A fragments: this wave's 128 i x 128 c (128 VGPRs)
    short8 afrag[8][4];
    {
        const short* ta = tT + ((long)b * HW + i0 + wv * 128) * CO;
        #pragma unroll
        for (int mt = 0; mt < 8; mt++)
            #pragma unroll
            for (int ks = 0; ks < 4; ks++)
                afrag[mt][ks] = *(const short8*)(ta + (mt * 16 + nrow) * CO + ks * 32 + quad * 8);
    }

    const short* pb2 = pT + (long)b * HW * CO + (long)j0 * CO;
    const int sc8 = tid & 15;            // 16B chunk within row
    const int sj0 = tid >> 4;            // 0..15

    short8 sreg[4];
    auto stage_load = [&](int jt) {      // global -> regs (coalesced 256B segs)
        const short* src = pb2 + (long)jt * 64 * CO;
        #pragma unroll
        for (int r = 0; r < 4; r++)
            sreg[r] = *(const short8*)(src + (sj0 + r * 16) * CO + sc8 * 8);
    };
    auto stage_write = [&](int buf) {    // regs -> LDS, swizzled chunk
        #pragma unroll
        for (int r = 0; r < 4; r++) {
            const int j  = sj0 + r * 16;
            const int c8 = sc8 ^ (j & 7);
            *(short8*)&bT[buf][j][c8 * 8] = sreg[r];
        }
    };

    f32x4 vmax[8];
    #pragma unroll
    for (int mt = 0; mt < 8; mt++)
        vmax[mt] = (f32x4){-1e30f, -1e30f, -1e30f, -1e30f};

    const f32x4 kz = {0.f, 0.f, 0.f, 0.f};   // hoisted MFMA C operand

    auto compute = [&](int buf) {
        #pragma unroll
        for (int np = 0; np < 2; np++) {      // nt pairs: j groups np*32, np*32+16
            short8 bf0[4], bf1[4];
            const int ja = np * 32 + nrow;
            const int jb = ja + 16;
            #pragma unroll
            for (int ks = 0; ks < 4; ks++) {
                bf0[ks] = *(const short8*)&bT[buf][ja][(((ks * 4 + quad) ^ (ja & 7)) * 8)];
                bf1[ks] = *(const short8*)&bT[buf][jb][(((ks * 4 + quad) ^ (jb & 7)) * 8)];
            }
            #pragma unroll
            for (int mt = 0; mt < 8; mt++) {
                f32x4 a0 = __builtin_amdgcn_mfma_f32_16x16x32_bf16(afrag[mt][0], bf0[0], kz, 0, 0, 0);
                f32x4 a1 = __builtin_amdgcn_mfma_f32_16x16x32_bf16(afrag[mt][0], bf1[0], kz, 0, 0, 0);
                #pragma unroll
                for (int ks = 1; ks < 4; ks++) {
                    a0 = __builtin_amdgcn_mfma_f32_16x16x32_bf16(afrag[mt][ks], bf0[ks], a0, 0, 0, 0);
                    a1 = __builtin_amdgcn_mfma_f32_16x16x32_bf16(afrag[mt][ks], bf1[ks], a1, 0, 0, 0);
                }
                #pragma unroll
                for (int r = 0; r < 4; r++)
                    vmax[mt][r] = fmaxf(fmaxf(a0[r], a1[r]), vmax[mt][r]);  // v_max3
            }
        }
    };

    stage_load(0);
    stage_write(0);
    for (int jt = 0; jt < 32; jt++) {
        __syncthreads();
        if (jt < 31) stage_load(jt + 1);     // prefetch overlaps MFMA below
        compute(jt & 1);
        if (jt < 31) stage_write((jt + 1) & 1);
    }

    // ---- reduce max over 16 j-columns (lane bits 0-3); each wave owns its 128 i
    #pragma unroll
    for (int mt = 0; mt < 8; mt++)
        #pragma unroll
        for (int r = 0; r < 4; r++) {
            float v = vmax[mt][r];
            #pragma unroll
            for (int m = 8; m >= 1; m >>= 1)
                v = fmaxf(v, __shfl_xor(v, m, 64));
            vmax[mt][r] = v;
        }

    if (nrow == 0) {
        float* pm = pmax + (size_t)jhalf * (B_ * HW) + (size_t)b * HW + i0 + wv * 128;
        #pragma unroll
        for (int mt = 0; mt < 8; mt++)
            #pragma unroll
            for (int r = 0; r < 4; r++)
                pm[mt * 16 + quad * 4 + r] = vmax[mt][r];
    }
}

// ---------------------------------------------------------------------------
// Combine the two j-half partial maxes, scale, sigmoid. 65536 outputs.
// ---------------------------------------------------------------------------
__global__ __launch_bounds__(256) void combine_kernel(
    const float* __restrict__ pmax, float* __restrict__ out)
{
    const int idx = blockIdx.x * 256 + threadIdx.x;   // < B_*HW
    const float v = fmaxf(pmax[idx], pmax[idx + B_ * HW]) * (1.0f / (float)HW);
    out[idx] = 1.0f / (1.0f + __expf(-v));
}

extern "C" void kernel_launch(void* const* d_in, const int* in_sizes, int n_in,
                              void* d_out, int out_size, void* d_ws, size_t ws_size,
                              hipStream_t stream) {
    const float* xg = (const float*)d_in[0];
    const float* xq = (const float*)d_in[1];
    const float* tw = (const float*)d_in[2];
    const float* tb = (const float*)d_in[3];
    const float* pw = (const float*)d_in[4];
    const float* pb = (const float*)d_in[5];
    float* out = (float*)d_out;

    short* tT  = (short*)d_ws;                         // [B][HW][CO] bf16, 16.78 MB
    short* pT  = tT + (size_t)B_ * HW * CO;            // [B][HW][CO] bf16, 16.78 MB
    short* wbf = pT + (size_t)B_ * HW * CO;            // [2][CO][CIN] bf16, 131 KB
    float* pmax = (float*)(wbf + 2 * CO * CIN);        // [2][B][HW] f32, 524 KB

    wconv_kernel<<<(2 * CO * CIN) / 256, 256, 0, stream>>>(tw, pw, wbf);
    proj_kernel<<<B_ * (HW / 64) * 2, 256, 0, stream>>>(xg, xq, tb, pb, wbf, tT, pT);
    maxgemm_kernel<<<B_ * (HW / 256), 256, 0, stream>>>(tT, pT, pmax);
    combine_kernel<<<(B_ * HW) / 256, 256, 0, stream>>>(pmax, out);
}

// Round 5
// 234.866 us; speedup vs baseline: 1.1431x; 1.1431x over previous
//
#include <hip/hip_runtime.h>
#include <hip/hip_bf16.h>

#define B_   16
#define CIN  256
#define CO   128
#define HW   4096

typedef __attribute__((ext_vector_type(8))) short short8;
typedef __attribute__((ext_vector_type(4))) float f32x4;
typedef __attribute__((ext_vector_type(4))) unsigned u32x4;

__device__ __forceinline__ short f32_to_bf16_rne(float f) {
    union { float f; unsigned u; } v; v.f = f;
    unsigned u = v.u;
    u += 0x7fffu + ((u >> 16) & 1u);
    return (short)(u >> 16);
}

// ---------------------------------------------------------------------------
// Weight pre-convert: wbf[0][co][ci] = bf16(theta_w), wbf[1][co][ci] = bf16(phi_w)
// ---------------------------------------------------------------------------
__global__ __launch_bounds__(256) void wconv_kernel(
    const float* __restrict__ tw, const float* __restrict__ pw,
    short* __restrict__ wbf)
{
    const int idx = blockIdx.x * 256 + threadIdx.x;     // 0 .. 2*CO*CIN-1
    const float v = (idx < CO * CIN) ? tw[idx] : pw[idx - CO * CIN];
    wbf[idx] = f32_to_bf16_rne(v);
}

// ---------------------------------------------------------------------------
// Projection v4: out_T[b][i][co] = sum_ci x[b][ci][i] * w[co][ci] + bias[co]
// grid 2048, block 256 (4 waves), XCD-swizzled by batch (b&7 == xcd).
// v4 change vs v3: ITILE IS THE FASTEST-VARYING block-index field.
// A block reads a 256B-wide column of a 16KB-pitch array -> address bits
// [13:8] are fixed per block (== itile). v3 varied itile slowest, so all
// concurrently-resident blocks shared ~1/3 of the bit[13:8] space ->
// channel/bank hot-spot capping the chip at ~1.8 TB/s (measured). Varying
// itile fastest spreads resident blocks across all 64 column positions.
// ---------------------------------------------------------------------------
__global__ __launch_bounds__(256, 4) void proj_kernel(
    const float* __restrict__ xg, const float* __restrict__ xq,
    const float* __restrict__ tb, const float* __restrict__ pb,
    const short* __restrict__ wbf,
    short* __restrict__ tT, short* __restrict__ pT)
{
    const int n     = blockIdx.x;
    const int xcd   = n & 7;
    const int q     = n >> 3;            // 0..255
    const int itile = q & 63;            // FASTEST: spreads addr bits [13:8]
    const int rr    = q >> 6;            // 0..3
    const int which = rr & 1;
    const int b     = xcd + 8 * (rr >> 1);

    const float* x    = which ? xq : xg;
    const float* bias = which ? pb : tb;
    const short* wb   = wbf + which * CO * CIN;
    short*       out  = which ? pT : tT;

    const int i0   = itile * 64;
    const int tid  = threadIdx.x;
    const int lane = tid & 63;
    const int wv   = tid >> 6;          // wave 0..3 -> co range [wv*32, wv*32+32)
    const int nrow = lane & 15;
    const int quad = lane >> 4;

    const int si   = tid & 63;          // row this thread stages (distinct per wave)
    const int cig  = tid >> 6;          // ci-group 0..3

    __shared__ __align__(16) short xT[2][64][64];   // [buf][i][ci] bf16, swizzled chunks

    f32x4 acc[4][2] = {};               // 4 m-subtiles (i) x 2 n-subtiles (co)

    float bias_v[2];
    bias_v[0] = bias[wv * 32 + 0  + nrow];
    bias_v[1] = bias[wv * 32 + 16 + nrow];

    const float* xb = x + (long)b * CIN * HW + i0 + si;   // this thread's i-column

    // ---- staging: 16 scalar f32 (stride HW) per thread per chunk
    float fst[2][8];
    auto stage_load = [&](int c) {
        const float* src = xb + (long)(c * 64) * HW;
        #pragma unroll
        for (int ro = 0; ro < 2; ro++)
            #pragma unroll
            for (int r = 0; r < 8; r++)
                fst[ro][r] = src[(long)((ro * 4 + cig) * 8 + r) * HW];
    };
    auto stage_write = [&](int buf) {
        #pragma unroll
        for (int ro = 0; ro < 2; ro++) {
            u32x4 d;
            #pragma unroll
            for (int p = 0; p < 4; p++) {
                const unsigned lo = (unsigned short)f32_to_bf16_rne(fst[ro][2 * p]);
                const unsigned hi = (unsigned short)f32_to_bf16_rne(fst[ro][2 * p + 1]);
                d[p] = lo | (hi << 16);
            }
            const int ck = (ro * 4 + cig) ^ (si & 7);   // XOR-swizzled 16B chunk
            *(u32x4*)&xT[buf][si][ck * 8] = d;
        }
    };

    // ---- weight fragments: double-buffered per chunk (32 VGPR)
    short8 wf[2][2][2];                 // [buf][ks][nt]
    auto wload = [&](int c, int buf) {
        #pragma unroll
        for (int ks = 0; ks < 2; ks++)
            #pragma unroll
            for (int nt = 0; nt < 2; nt++)
                wf[buf][ks][nt] = *(const short8*)(
                    wb + (wv * 32 + nt * 16 + nrow) * CIN + c * 64 + ks * 32 + quad * 8);
    };

    auto compute = [&](int buf) {
        #pragma unroll
        for (int ks = 0; ks < 2; ks++)
            #pragma unroll
            for (int mt = 0; mt < 4; mt++) {
                const int row = mt * 16 + nrow;
                const int ck  = (ks * 4 + quad) ^ (row & 7);
                const short8 a = *(const short8*)&xT[buf][row][ck * 8];
                acc[mt][0] = __builtin_amdgcn_mfma_f32_16x16x32_bf16(a, wf[buf][ks][0], acc[mt][0], 0, 0, 0);
                acc[mt][1] = __builtin_amdgcn_mfma_f32_16x16x32_bf16(a, wf[buf][ks][1], acc[mt][1], 0, 0, 0);
            }
    };

    wload(0, 0);
    stage_load(0);
    stage_write(0);
    #pragma unroll
    for (int c = 0; c < 4; c++) {
        __syncthreads();
        if (c < 3) { stage_load(c + 1); wload(c + 1, (c + 1) & 1); }  // deep prefetch
        compute(c & 1);
        if (c < 3) stage_write((c + 1) & 1);
    }

    // ---- store: D layout col = lane&15 (co), row = quad*4 + reg (i)
    #pragma unroll
    for (int mt = 0; mt < 4; mt++)
        #pragma unroll
        for (int nt = 0; nt < 2; nt++) {
            const int co = wv * 32 + nt * 16 + nrow;
            #pragma unroll
            for (int r = 0; r < 4; r++) {
                const int il = mt * 16 + quad * 4 + r;
                out[((long)b * HW + i0 + il) * CO + co] =
                    f32_to_bf16_rne(acc[mt][nt][r] + bias_v[nt]);
            }
        }
}

// ---------------------------------------------------------------------------
// Max-GEMM v2: pmax[jh][b][i] = max_{j in half jh} sum_c tT[b][i][c]*pT[b][j][c]
// (unchanged)
// ---------------------------------------------------------------------------
__global__ __launch_bounds__(256, 1) void maxgemm_kernel(
    const short* __restrict__ tT, const short* __restrict__ pT,
    float* __restrict__ pmax)
{
    const int n     = blockIdx.x;
    const int b     = (n & 7) + 8 * ((n >> 3) & 1);
    const int mm    = n >> 4;            // 0..15
    const int itile = mm & 7;            // 0..7
    const int jhalf = mm >> 3;           // 0..1
    const int i0    = itile * 512;
    const int j0    = jhalf * 2048;
    const int tid   = threadIdx.x;
    const int lane  = tid & 63;
    const int wv    = tid >> 6;
    const int nrow  = lane & 15;
    const int quad  = lane >> 4;

    __shared__ short bT[2][64][128];     // 32 KB, unpadded, XOR-swizzled chunks

    // ---- loop-invariant A fragments: this wave's 128 i x 128 c (128 VGPRs)
    short8 afrag[8][4];
    {
        const short* ta = tT + ((long)b * HW + i0 + wv * 128) * CO;
        #pragma unroll
        for (int mt = 0; mt < 8; mt++)
            #pragma unroll
            for (int ks = 0; ks < 4; ks++)
                afrag[mt][ks] = *(const short8*)(ta + (mt * 16 + nrow) * CO + ks * 32 + quad * 8);
    }

    const short* pb2 = pT + (long)b * HW * CO + (long)j0 * CO;
    const int sc8 = tid & 15;            // 16B chunk within row
    const int sj0 = tid >> 4;            // 0..15

    short8 sreg[4];
    auto stage_load = [&](int jt) {      // global -> regs (coalesced 256B segs)
        const short* src = pb2 + (long)jt * 64 * CO;
        #pragma unroll
        for (int r = 0; r < 4; r++)
            sreg[r] = *(const short8*)(src + (sj0 + r * 16) * CO + sc8 * 8);
    };
    auto stage_write = [&](int buf) {    // regs -> LDS, swizzled chunk
        #pragma unroll
        for (int r = 0; r < 4; r++) {
            const int j  = sj0 + r * 16;
            const int c8 = sc8 ^ (j & 7);
            *(short8*)&bT[buf][j][c8 * 8] = sreg[r];
        }
    };

    f32x4 vmax[8];
    #pragma unroll
    for (int mt = 0; mt < 8; mt++)
        vmax[mt] = (f32x4){-1e30f, -1e30f, -1e30f, -1e30f};

    const f32x4 kz = {0.f, 0.f, 0.f, 0.f};   // hoisted MFMA C operand

    auto compute = [&](int buf) {
        #pragma unroll
        for (int np = 0; np < 2; np++) {      // nt pairs: j groups np*32, np*32+16
            short8 bf0[4], bf1[4];
            const int ja = np * 32 + nrow;
            const int jb = ja + 16;
            #pragma unroll
            for (int ks = 0; ks < 4; ks++) {
                bf0[ks] = *(const short8*)&bT[buf][ja][(((ks * 4 + quad) ^ (ja & 7)) * 8)];
                bf1[ks] = *(const short8*)&bT[buf][jb][(((ks * 4 + quad) ^ (jb & 7)) * 8)];
            }
            #pragma unroll
            for (int mt = 0; mt < 8; mt++) {
                f32x4 a0 = __builtin_amdgcn_mfma_f32_16x16x32_bf16(afrag[mt][0], bf0[0], kz, 0, 0, 0);
                f32x4 a1 = __builtin_amdgcn_mfma_f32_16x16x32_bf16(afrag[mt][0], bf1[0], kz, 0, 0, 0);
                #pragma unroll
                for (int ks = 1; ks < 4; ks++) {
                    a0 = __builtin_amdgcn_mfma_f32_16x16x32_bf16(afrag[mt][ks], bf0[ks], a0, 0, 0, 0);
                    a1 = __builtin_amdgcn_mfma_f32_16x16x32_bf16(afrag[mt][ks], bf1[ks], a1, 0, 0, 0);
                }
                #pragma unroll
                for (int r = 0; r < 4; r++)
                    vmax[mt][r] = fmaxf(fmaxf(a0[r], a1[r]), vmax[mt][r]);  // v_max3
            }
        }
    };

    stage_load(0);
    stage_write(0);
    for (int jt = 0; jt < 32; jt++) {
        __syncthreads();
        if (jt < 31) stage_load(jt + 1);     // prefetch overlaps MFMA below
        compute(jt & 1);
        if (jt < 31) stage_write((jt + 1) & 1);
    }

    // ---- reduce max over 16 j-columns (lane bits 0-3); each wave owns its 128 i
    #pragma unroll
    for (int mt = 0; mt < 8; mt++)
        #pragma unroll
        for (int r = 0; r < 4; r++) {
            float v = vmax[mt][r];
            #pragma unroll
            for (int m = 8; m >= 1; m >>= 1)
                v = fmaxf(v, __shfl_xor(v, m, 64));
            vmax[mt][r] = v;
        }

    if (nrow == 0) {
        float* pm = pmax + (size_t)jhalf * (B_ * HW) + (size_t)b * HW + i0 + wv * 128;
        #pragma unroll
        for (int mt = 0; mt < 8; mt++)
            #pragma unroll
            for (int r = 0; r < 4; r++)
                pm[mt * 16 + quad * 4 + r] = vmax[mt][r];
    }
}

// ---------------------------------------------------------------------------
// Combine the two j-half partial maxes, scale, sigmoid. 65536 outputs.
// ---------------------------------------------------------------------------
__global__ __launch_bounds__(256) void combine_kernel(
    const float* __restrict__ pmax, float* __restrict__ out)
{
    const int idx = blockIdx.x * 256 + threadIdx.x;   // < B_*HW
    const float v = fmaxf(pmax[idx], pmax[idx + B_ * HW]) * (1.0f / (float)HW);
    out[idx] = 1.0f / (1.0f + __expf(-v));
}

extern "C" void kernel_launch(void* const* d_in, const int* in_sizes, int n_in,
                              void* d_out, int out_size, void* d_ws, size_t ws_size,
                              hipStream_t stream) {
    const float* xg = (const float*)d_in[0];
    const float* xq = (const float*)d_in[1];
    const float* tw = (const float*)d_in[2];
    const float* tb = (const float*)d_in[3];
    const float* pw = (const float*)d_in[4];
    const float* pb = (const float*)d_in[5];
    float* out = (float*)d_out;

    short* tT  = (short*)d_ws;                         // [B][HW][CO] bf16, 16.78 MB
    short* pT  = tT + (size_t)B_ * HW * CO;            // [B][HW][CO] bf16, 16.78 MB
    short* wbf = pT + (size_t)B_ * HW * CO;            // [2][CO][CIN] bf16, 131 KB
    float* pmax = (float*)(wbf + 2 * CO * CIN);        // [2][B][HW] f32, 524 KB

    wconv_kernel<<<(2 * CO * CIN) / 256, 256, 0, stream>>>(tw, pw, wbf);
    proj_kernel<<<B_ * (HW / 64) * 2, 256, 0, stream>>>(xg, xq, tb, pb, wbf, tT, pT);
    maxgemm_kernel<<<B_ * (HW / 256), 256, 0, stream>>>(tT, pT, pmax);
    combine_kernel<<<(B_ * HW) / 256, 256, 0, stream>>>(pmax, out);
}

// Round 6
// 224.758 us; speedup vs baseline: 1.1945x; 1.0450x over previous
//
#include <hip/hip_runtime.h>
#include <hip/hip_bf16.h>

#define B_   16
#define CIN  256
#define CO   128
#define HW   4096

typedef __attribute__((ext_vector_type(8))) short short8;
typedef __attribute__((ext_vector_type(4))) float f32x4;
typedef __attribute__((ext_vector_type(4))) unsigned u32x4;

__device__ __forceinline__ short f32_to_bf16_rne(float f) {
    union { float f; unsigned u; } v; v.f = f;
    unsigned u = v.u;
    u += 0x7fffu + ((u >> 16) & 1u);
    return (short)(u >> 16);
}

// ---------------------------------------------------------------------------
// Weight pre-convert: wbf[0][co][ci] = bf16(theta_w), wbf[1][co][ci] = bf16(phi_w)
// ---------------------------------------------------------------------------
__global__ __launch_bounds__(256) void wconv_kernel(
    const float* __restrict__ tw, const float* __restrict__ pw,
    short* __restrict__ wbf)
{
    const int idx = blockIdx.x * 256 + threadIdx.x;     // 0 .. 2*CO*CIN-1
    const float v = (idx < CO * CIN) ? tw[idx] : pw[idx - CO * CIN];
    wbf[idx] = f32_to_bf16_rne(v);
}

// ---------------------------------------------------------------------------
// Projection v4: out_T[b][i][co] = sum_ci x[b][ci][i] * w[co][ci] + bias[co]
// grid 2048, block 256 (4 waves), XCD-swizzled by batch (b&7 == xcd).
// itile is the FASTEST-varying block-index field: a block reads a 256B-wide
// column of a 16KB-pitch array (addr bits [13:8] fixed = itile); varying
// itile fastest spreads resident blocks across all 64 column positions ->
// fixed the channel hot-spot that capped v3 at ~1.8 TB/s (proved round 5:
// proj 74 -> ~41 us).
// ---------------------------------------------------------------------------
__global__ __launch_bounds__(256, 4) void proj_kernel(
    const float* __restrict__ xg, const float* __restrict__ xq,
    const float* __restrict__ tb, const float* __restrict__ pb,
    const short* __restrict__ wbf,
    short* __restrict__ tT, short* __restrict__ pT)
{
    const int n     = blockIdx.x;
    const int xcd   = n & 7;
    const int q     = n >> 3;            // 0..255
    const int itile = q & 63;            // FASTEST: spreads addr bits [13:8]
    const int rr    = q >> 6;            // 0..3
    const int which = rr & 1;
    const int b     = xcd + 8 * (rr >> 1);

    const float* x    = which ? xq : xg;
    const float* bias = which ? pb : tb;
    const short* wb   = wbf + which * CO * CIN;
    short*       out  = which ? pT : tT;

    const int i0   = itile * 64;
    const int tid  = threadIdx.x;
    const int lane = tid & 63;
    const int wv   = tid >> 6;          // wave 0..3 -> co range [wv*32, wv*32+32)
    const int nrow = lane & 15;
    const int quad = lane >> 4;

    const int si   = tid & 63;          // row this thread stages (distinct per wave)
    const int cig  = tid >> 6;          // ci-group 0..3

    __shared__ __align__(16) short xT[2][64][64];   // [buf][i][ci] bf16, swizzled chunks

    f32x4 acc[4][2] = {};               // 4 m-subtiles (i) x 2 n-subtiles (co)

    float bias_v[2];
    bias_v[0] = bias[wv * 32 + 0  + nrow];
    bias_v[1] = bias[wv * 32 + 16 + nrow];

    const float* xb = x + (long)b * CIN * HW + i0 + si;   // this thread's i-column

    // ---- staging: 16 scalar f32 (stride HW) per thread per chunk
    float fst[2][8];
    auto stage_load = [&](int c) {
        const float* src = xb + (long)(c * 64) * HW;
        #pragma unroll
        for (int ro = 0; ro < 2; ro++)
            #pragma unroll
            for (int r = 0; r < 8; r++)
                fst[ro][r] = src[(long)((ro * 4 + cig) * 8 + r) * HW];
    };
    auto stage_write = [&](int buf) {
        #pragma unroll
        for (int ro = 0; ro < 2; ro++) {
            u32x4 d;
            #pragma unroll
            for (int p = 0; p < 4; p++) {
                const unsigned lo = (unsigned short)f32_to_bf16_rne(fst[ro][2 * p]);
                const unsigned hi = (unsigned short)f32_to_bf16_rne(fst[ro][2 * p + 1]);
                d[p] = lo | (hi << 16);
            }
            const int ck = (ro * 4 + cig) ^ (si & 7);   // XOR-swizzled 16B chunk
            *(u32x4*)&xT[buf][si][ck * 8] = d;
        }
    };

    // ---- weight fragments: double-buffered per chunk (32 VGPR)
    short8 wf[2][2][2];                 // [buf][ks][nt]
    auto wload = [&](int c, int buf) {
        #pragma unroll
        for (int ks = 0; ks < 2; ks++)
            #pragma unroll
            for (int nt = 0; nt < 2; nt++)
                wf[buf][ks][nt] = *(const short8*)(
                    wb + (wv * 32 + nt * 16 + nrow) * CIN + c * 64 + ks * 32 + quad * 8);
    };

    auto compute = [&](int buf) {
        #pragma unroll
        for (int ks = 0; ks < 2; ks++)
            #pragma unroll
            for (int mt = 0; mt < 4; mt++) {
                const int row = mt * 16 + nrow;
                const int ck  = (ks * 4 + quad) ^ (row & 7);
                const short8 a = *(const short8*)&xT[buf][row][ck * 8];
                acc[mt][0] = __builtin_amdgcn_mfma_f32_16x16x32_bf16(a, wf[buf][ks][0], acc[mt][0], 0, 0, 0);
                acc[mt][1] = __builtin_amdgcn_mfma_f32_16x16x32_bf16(a, wf[buf][ks][1], acc[mt][1], 0, 0, 0);
            }
    };

    wload(0, 0);
    stage_load(0);
    stage_write(0);
    #pragma unroll
    for (int c = 0; c < 4; c++) {
        __syncthreads();
        if (c < 3) { stage_load(c + 1); wload(c + 1, (c + 1) & 1); }  // deep prefetch
        compute(c & 1);
        if (c < 3) stage_write((c + 1) & 1);
    }

    // ---- store: D layout col = lane&15 (co), row = quad*4 + reg (i)
    #pragma unroll
    for (int mt = 0; mt < 4; mt++)
        #pragma unroll
        for (int nt = 0; nt < 2; nt++) {
            const int co = wv * 32 + nt * 16 + nrow;
            #pragma unroll
            for (int r = 0; r < 4; r++) {
                const int il = mt * 16 + quad * 4 + r;
                out[((long)b * HW + i0 + il) * CO + co] =
                    f32_to_bf16_rne(acc[mt][nt][r] + bias_v[nt]);
            }
        }
}

// ---------------------------------------------------------------------------
// Max-GEMM v3: pmax[jq][b][i] = max_{j in quarter jq} sum_c tT[b][i][c]*pT[b][j][c]
// v3 change vs v2: 2 BLOCKS PER CU (grid 512, launch_bounds(256,2)).
// v2 ran 1 wave/SIMD (occupancy 10%) -> every ds_read latency, global
// prefetch and barrier drain sat on the critical path (5360 cyc/jt measured
// vs ~960 throughput ledger). j is split into QUARTERS (1024 j = 16 jt per
// block); per-wave i stays 128 so the MFMA:LDS ratio is unchanged; second
// resident wave per SIMD hides the latency. Regs ~230/wave fits the 256
// budget 2 waves/SIMD requires.
// ---------------------------------------------------------------------------
__global__ __launch_bounds__(256, 2) void maxgemm_kernel(
    const short* __restrict__ tT, const short* __restrict__ pT,
    float* __restrict__ pmax)
{
    const int n     = blockIdx.x;        // 0..511
    const int b     = (n & 7) + 8 * ((n >> 3) & 1);
    const int mm    = n >> 4;            // 0..31
    const int itile = mm & 7;            // 0..7
    const int jq    = mm >> 3;           // 0..3
    const int i0    = itile * 512;
    const int j0    = jq * 1024;
    const int tid   = threadIdx.x;
    const int lane  = tid & 63;
    const int wv    = tid >> 6;
    const int nrow  = lane & 15;
    const int quad  = lane >> 4;

    __shared__ short bT[2][64][128];     // 32 KB, unpadded, XOR-swizzled chunks

    // ---- loop-invariant A fragments: this wave's 128 i x 128 c (128 VGPRs)
    short8 afrag[8][4];
    {
        const short* ta = tT + ((long)b * HW + i0 + wv * 128) * CO;
        #pragma unroll
        for (int mt = 0; mt < 8; mt++)
            #pragma unroll
            for (int ks = 0; ks < 4; ks++)
                afrag[mt][ks] = *(const short8*)(ta + (mt * 16 + nrow) * CO + ks * 32 + quad * 8);
    }

    const short* pb2 = pT + (long)b * HW * CO + (long)j0 * CO;
    const int sc8 = tid & 15;            // 16B chunk within row
    const int sj0 = tid >> 4;            // 0..15

    short8 sreg[4];
    auto stage_load = [&](int jt) {      // global -> regs (coalesced 256B segs)
        const short* src = pb2 + (long)jt * 64 * CO;
        #pragma unroll
        for (int r = 0; r < 4; r++)
            sreg[r] = *(const short8*)(src + (sj0 + r * 16) * CO + sc8 * 8);
    };
    auto stage_write = [&](int buf) {    // regs -> LDS, swizzled chunk
        #pragma unroll
        for (int r = 0; r < 4; r++) {
            const int j  = sj0 + r * 16;
            const int c8 = sc8 ^ (j & 7);
            *(short8*)&bT[buf][j][c8 * 8] = sreg[r];
        }
    };

    f32x4 vmax[8];
    #pragma unroll
    for (int mt = 0; mt < 8; mt++)
        vmax[mt] = (f32x4){-1e30f, -1e30f, -1e30f, -1e30f};

    const f32x4 kz = {0.f, 0.f, 0.f, 0.f};   // hoisted MFMA C operand

    auto compute = [&](int buf) {
        #pragma unroll
        for (int np = 0; np < 2; np++) {      // nt pairs: j groups np*32, np*32+16
            short8 bf0[4], bf1[4];
            const int ja = np * 32 + nrow;
            const int jb = ja + 16;
            #pragma unroll
            for (int ks = 0; ks < 4; ks++) {
                bf0[ks] = *(const short8*)&bT[buf][ja][(((ks * 4 + quad) ^ (ja & 7)) * 8)];
                bf1[ks] = *(const short8*)&bT[buf][jb][(((ks * 4 + quad) ^ (jb & 7)) * 8)];
            }
            #pragma unroll
            for (int mt = 0; mt < 8; mt++) {
                f32x4 a0 = __builtin_amdgcn_mfma_f32_16x16x32_bf16(afrag[mt][0], bf0[0], kz, 0, 0, 0);
                f32x4 a1 = __builtin_amdgcn_mfma_f32_16x16x32_bf16(afrag[mt][0], bf1[0], kz, 0, 0, 0);
                #pragma unroll
                for (int ks = 1; ks < 4; ks++) {
                    a0 = __builtin_amdgcn_mfma_f32_16x16x32_bf16(afrag[mt][ks], bf0[ks], a0, 0, 0, 0);
                    a1 = __builtin_amdgcn_mfma_f32_16x16x32_bf16(afrag[mt][ks], bf1[ks], a1, 0, 0, 0);
                }
                #pragma unroll
                for (int r = 0; r < 4; r++)
                    vmax[mt][r] = fmaxf(fmaxf(a0[r], a1[r]), vmax[mt][r]);  // v_max3
            }
        }
    };

    stage_load(0);
    stage_write(0);
    for (int jt = 0; jt < 16; jt++) {
        __syncthreads();
        if (jt < 15) stage_load(jt + 1);     // prefetch overlaps MFMA below
        compute(jt & 1);
        if (jt < 15) stage_write((jt + 1) & 1);
    }

    // ---- reduce max over 16 j-columns (lane bits 0-3); each wave owns its 128 i
    #pragma unroll
    for (int mt = 0; mt < 8; mt++)
        #pragma unroll
        for (int r = 0; r < 4; r++) {
            float v = vmax[mt][r];
            #pragma unroll
            for (int m = 8; m >= 1; m >>= 1)
                v = fmaxf(v, __shfl_xor(v, m, 64));
            vmax[mt][r] = v;
        }

    if (nrow == 0) {
        float* pm = pmax + (size_t)jq * (B_ * HW) + (size_t)b * HW + i0 + wv * 128;
        #pragma unroll
        for (int mt = 0; mt < 8; mt++)
            #pragma unroll
            for (int r = 0; r < 4; r++)
                pm[mt * 16 + quad * 4 + r] = vmax[mt][r];
    }
}

// ---------------------------------------------------------------------------
// Combine the four j-quarter partial maxes, scale, sigmoid. 65536 outputs.
// ---------------------------------------------------------------------------
__global__ __launch_bounds__(256) void combine_kernel(
    const float* __restrict__ pmax, float* __restrict__ out)
{
    const int idx = blockIdx.x * 256 + threadIdx.x;   // < B_*HW
    float v = pmax[idx];
    #pragma unroll
    for (int p = 1; p < 4; p++)
        v = fmaxf(v, pmax[idx + p * (B_ * HW)]);
    v *= (1.0f / (float)HW);
    out[idx] = 1.0f / (1.0f + __expf(-v));
}

extern "C" void kernel_launch(void* const* d_in, const int* in_sizes, int n_in,
                              void* d_out, int out_size, void* d_ws, size_t ws_size,
                              hipStream_t stream) {
    const float* xg = (const float*)d_in[0];
    const float* xq = (const float*)d_in[1];
    const float* tw = (const float*)d_in[2];
    const float* tb = (const float*)d_in[3];
    const float* pw = (const float*)d_in[4];
    const float* pb = (const float*)d_in[5];
    float* out = (float*)d_out;

    short* tT  = (short*)d_ws;                         // [B][HW][CO] bf16, 16.78 MB
    short* pT  = tT + (size_t)B_ * HW * CO;            // [B][HW][CO] bf16, 16.78 MB
    short* wbf = pT + (size_t)B_ * HW * CO;            // [2][CO][CIN] bf16, 131 KB
    float* pmax = (float*)(wbf + 2 * CO * CIN);        // [4][B][HW] f32, 1.05 MB

    wconv_kernel<<<(2 * CO * CIN) / 256, 256, 0, stream>>>(tw, pw, wbf);
    proj_kernel<<<B_ * (HW / 64) * 2, 256, 0, stream>>>(xg, xq, tb, pb, wbf, tT, pT);
    maxgemm_kernel<<<B_ * (HW / 512) * 4, 256, 0, stream>>>(tT, pT, pmax);
    combine_kernel<<<(B_ * HW) / 256, 256, 0, stream>>>(pmax, out);
}